// Round 1
// baseline (160.653 us; speedup 1.0000x reference)
//
#include <hip/hip_runtime.h>
#include <math.h>

#define DIM  512
#define H2   512
#define BSZ  384

#define TM 64
#define TN 64
#define TK 16

// ---------------------------------------------------------------------------
// ws layout (floats):
//   hmu  : [384*512]          @ 0
//   hlv  : [384*512]          @ 196608
//   m1p  : [6*512] partials   @ 393216
//   m2p  : [6*512] partials   @ 396288
//   part : [48] doubles       @ 399360 (byte off 1597440, 8B aligned)
// total ~1.6 MB
// ---------------------------------------------------------------------------

// Kernel 1: layer-1 GEMMs h = relu(x @ W1 + b1) for mu (z=0) and lv (z=1),
// plus y column moments partials (z=2). grid (8,6,3), block 256.
__global__ __launch_bounds__(256) void k_layer1(
    const float* __restrict__ x,
    const float* __restrict__ w1mu, const float* __restrict__ b1mu,
    const float* __restrict__ w1lv, const float* __restrict__ b1lv,
    const float* __restrict__ y,
    float* __restrict__ hmu, float* __restrict__ hlv,
    float* __restrict__ m1p, float* __restrict__ m2p)
{
    const int tid = threadIdx.x;
    const int bx = blockIdx.x, by = blockIdx.y, bz = blockIdx.z;

    if (bz == 2) {
        // y column stats over a 64x64 tile: rows by*64.., cols bx*64..
        __shared__ float red[2][4][64];
        const int col = tid & 63, part = tid >> 6;
        const int c = bx * 64 + col;
        const int r0 = by * 64 + part * 16;
        float s1 = 0.f, s2 = 0.f;
        #pragma unroll
        for (int r = 0; r < 16; ++r) {
            float v = y[(size_t)(r0 + r) * DIM + c];
            s1 += v; s2 += v * v;
        }
        red[0][part][col] = s1; red[1][part][col] = s2;
        __syncthreads();
        if (part == 0) {
            m1p[by * DIM + c] = red[0][0][col] + red[0][1][col] + red[0][2][col] + red[0][3][col];
            m2p[by * DIM + c] = red[1][0][col] + red[1][1][col] + red[1][2][col] + red[1][3][col];
        }
        return;
    }

    const float* __restrict__ W    = bz ? w1lv : w1mu;
    const float* __restrict__ bias = bz ? b1lv : b1mu;
    float* __restrict__ H          = bz ? hlv : hmu;

    __shared__ float As[TM][TK];
    __shared__ float Bs[TK][TN];

    const int tx = tid & 15, ty = tid >> 4;
    const int m0 = by * TM, n0 = bx * TN;
    const int arow = tid >> 2, aseg = (tid & 3) * 4;
    const int brow = tid >> 4, bcol = (tid & 15) * 4;

    float acc[4][4] = {};

    for (int k0 = 0; k0 < DIM; k0 += TK) {
        float4 av = *(const float4*)&x[(size_t)(m0 + arow) * DIM + k0 + aseg];
        float4 bv = *(const float4*)&W[(size_t)(k0 + brow) * H2 + n0 + bcol];
        __syncthreads();
        *(float4*)&As[arow][aseg] = av;
        *(float4*)&Bs[brow][bcol] = bv;
        __syncthreads();
        #pragma unroll
        for (int kk = 0; kk < TK; ++kk) {
            float a0 = As[ty*4+0][kk], a1 = As[ty*4+1][kk];
            float a2 = As[ty*4+2][kk], a3 = As[ty*4+3][kk];
            float4 b = *(const float4*)&Bs[kk][tx*4];
            acc[0][0] += a0*b.x; acc[0][1] += a0*b.y; acc[0][2] += a0*b.z; acc[0][3] += a0*b.w;
            acc[1][0] += a1*b.x; acc[1][1] += a1*b.y; acc[1][2] += a1*b.z; acc[1][3] += a1*b.w;
            acc[2][0] += a2*b.x; acc[2][1] += a2*b.y; acc[2][2] += a2*b.z; acc[2][3] += a2*b.w;
            acc[3][0] += a3*b.x; acc[3][1] += a3*b.y; acc[3][2] += a3*b.z; acc[3][3] += a3*b.w;
        }
    }

    float bb[4];
    *(float4*)bb = *(const float4*)&bias[n0 + tx*4];
    #pragma unroll
    for (int i = 0; i < 4; ++i) {
        float4 o;
        o.x = fmaxf(acc[i][0] + bb[0], 0.f);
        o.y = fmaxf(acc[i][1] + bb[1], 0.f);
        o.z = fmaxf(acc[i][2] + bb[2], 0.f);
        o.w = fmaxf(acc[i][3] + bb[3], 0.f);
        *(float4*)&H[(size_t)(m0 + ty*4 + i) * H2 + n0 + tx*4] = o;
    }
}

// Kernel 2: layer-2 double GEMM (mu and lv tiles in one block) + analytic
// epilogue, block-level reduction to a double partial. grid (8,6), block 256.
__global__ __launch_bounds__(256) void k_layer2(
    const float* __restrict__ hmu, const float* __restrict__ hlv,
    const float* __restrict__ w2mu, const float* __restrict__ b2mu,
    const float* __restrict__ w2lv, const float* __restrict__ b2lv,
    const float* __restrict__ y,
    const float* __restrict__ m1p, const float* __restrict__ m2p,
    double* __restrict__ partials)
{
    __shared__ float Am[TM][TK];
    __shared__ float Al[TM][TK];
    __shared__ float Bm[TK][TN];
    __shared__ float Bl[TK][TN];
    __shared__ double wsum[4];

    const int tid = threadIdx.x;
    const int bx = blockIdx.x, by = blockIdx.y;
    const int tx = tid & 15, ty = tid >> 4;
    const int m0 = by * TM, n0 = bx * TN;
    const int arow = tid >> 2, aseg = (tid & 3) * 4;
    const int brow = tid >> 4, bcol = (tid & 15) * 4;

    float accm[4][4] = {};
    float accl[4][4] = {};

    for (int k0 = 0; k0 < H2; k0 += TK) {
        float4 am = *(const float4*)&hmu[(size_t)(m0 + arow) * H2 + k0 + aseg];
        float4 al = *(const float4*)&hlv[(size_t)(m0 + arow) * H2 + k0 + aseg];
        float4 bm = *(const float4*)&w2mu[(size_t)(k0 + brow) * DIM + n0 + bcol];
        float4 bl = *(const float4*)&w2lv[(size_t)(k0 + brow) * DIM + n0 + bcol];
        __syncthreads();
        *(float4*)&Am[arow][aseg] = am;
        *(float4*)&Al[arow][aseg] = al;
        *(float4*)&Bm[brow][bcol] = bm;
        *(float4*)&Bl[brow][bcol] = bl;
        __syncthreads();
        #pragma unroll
        for (int kk = 0; kk < TK; ++kk) {
            float am0 = Am[ty*4+0][kk], am1 = Am[ty*4+1][kk];
            float am2 = Am[ty*4+2][kk], am3 = Am[ty*4+3][kk];
            float4 b = *(const float4*)&Bm[kk][tx*4];
            accm[0][0] += am0*b.x; accm[0][1] += am0*b.y; accm[0][2] += am0*b.z; accm[0][3] += am0*b.w;
            accm[1][0] += am1*b.x; accm[1][1] += am1*b.y; accm[1][2] += am1*b.z; accm[1][3] += am1*b.w;
            accm[2][0] += am2*b.x; accm[2][1] += am2*b.y; accm[2][2] += am2*b.z; accm[2][3] += am2*b.w;
            accm[3][0] += am3*b.x; accm[3][1] += am3*b.y; accm[3][2] += am3*b.z; accm[3][3] += am3*b.w;
            float al0 = Al[ty*4+0][kk], al1 = Al[ty*4+1][kk];
            float al2 = Al[ty*4+2][kk], al3 = Al[ty*4+3][kk];
            float4 c = *(const float4*)&Bl[kk][tx*4];
            accl[0][0] += al0*c.x; accl[0][1] += al0*c.y; accl[0][2] += al0*c.z; accl[0][3] += al0*c.w;
            accl[1][0] += al1*c.x; accl[1][1] += al1*c.y; accl[1][2] += al1*c.z; accl[1][3] += al1*c.w;
            accl[2][0] += al2*c.x; accl[2][1] += al2*c.y; accl[2][2] += al2*c.z; accl[2][3] += al2*c.w;
            accl[3][0] += al3*c.x; accl[3][1] += al3*c.y; accl[3][2] += al3*c.z; accl[3][3] += al3*c.w;
        }
    }

    // Epilogue: term = inv_var * ((y^2 - m2) + 2*mu*(m1 - y)) per element.
    const float inv_b = 1.0f / (float)BSZ;
    float bmv[4], blv_[4], m1v[4], m2v[4];
    *(float4*)bmv  = *(const float4*)&b2mu[n0 + tx*4];
    *(float4*)blv_ = *(const float4*)&b2lv[n0 + tx*4];
    #pragma unroll
    for (int j = 0; j < 4; ++j) {
        const int c = n0 + tx*4 + j;
        float s1 = 0.f, s2 = 0.f;
        #pragma unroll
        for (int t = 0; t < 6; ++t) { s1 += m1p[t*DIM + c]; s2 += m2p[t*DIM + c]; }
        m1v[j] = s1 * inv_b; m2v[j] = s2 * inv_b;
    }

    float tsum = 0.f;
    #pragma unroll
    for (int i = 0; i < 4; ++i) {
        const int r = m0 + ty*4 + i;
        float yv[4];
        *(float4*)yv = *(const float4*)&y[(size_t)r * DIM + n0 + tx*4];
        #pragma unroll
        for (int j = 0; j < 4; ++j) {
            float mu = accm[i][j] + bmv[j];
            float lv = tanhf(accl[i][j] + blv_[j]);
            float iv = expf(-lv);
            tsum += iv * ((yv[j]*yv[j] - m2v[j]) + 2.f*mu*(m1v[j] - yv[j]));
        }
    }

    // block reduction: wave shuffle then cross-wave via LDS (double)
    float s = tsum;
    #pragma unroll
    for (int off = 32; off > 0; off >>= 1) s += __shfl_down(s, off);
    if ((tid & 63) == 0) wsum[tid >> 6] = (double)s;
    __syncthreads();
    if (tid == 0)
        partials[by * gridDim.x + bx] = wsum[0] + wsum[1] + wsum[2] + wsum[3];
}

// Kernel 3: reduce 48 double partials -> scalar output.
__global__ void k_final(const double* __restrict__ partials, float* __restrict__ out)
{
    const int t = threadIdx.x;
    double v = (t < 48) ? partials[t] : 0.0;
    #pragma unroll
    for (int off = 32; off > 0; off >>= 1) v += __shfl_down(v, off);
    if (t == 0) {
        // C0 = log1p(exp(-20)/383) — the broadcast-bug logsumexp constant
        const double C0 = 5.381602146862063e-12;
        out[0] = (float)(-0.5 * v / (double)BSZ - C0);
    }
}

extern "C" void kernel_launch(void* const* d_in, const int* in_sizes, int n_in,
                              void* d_out, int out_size, void* d_ws, size_t ws_size,
                              hipStream_t stream) {
    const float* x    = (const float*)d_in[0];
    const float* y    = (const float*)d_in[1];
    const float* w1mu = (const float*)d_in[2];
    const float* b1mu = (const float*)d_in[3];
    const float* w2mu = (const float*)d_in[4];
    const float* b2mu = (const float*)d_in[5];
    const float* w1lv = (const float*)d_in[6];
    const float* b1lv = (const float*)d_in[7];
    const float* w2lv = (const float*)d_in[8];
    const float* b2lv = (const float*)d_in[9];
    float* out = (float*)d_out;

    float* ws   = (float*)d_ws;
    float* hmu  = ws;
    float* hlv  = ws + 196608;
    float* m1p  = ws + 393216;
    float* m2p  = ws + 396288;
    double* partials = (double*)(ws + 399360);

    k_layer1<<<dim3(8, 6, 3), 256, 0, stream>>>(x, w1mu, b1mu, w1lv, b1lv, y,
                                                hmu, hlv, m1p, m2p);
    k_layer2<<<dim3(8, 6), 256, 0, stream>>>(hmu, hlv, w2mu, b2mu, w2lv, b2lv,
                                             y, m1p, m2p, partials);
    k_final<<<1, 64, 0, stream>>>(partials, out);
}

// Round 2
// 111.831 us; speedup vs baseline: 1.4366x; 1.4366x over previous
//
#include <hip/hip_runtime.h>
#include <math.h>

#define DIM  512
#define H2   512
#define BSZ  384

// GEMM tile: 32 (M) x 64 (N), TK=32, 256 threads, micro-tile 2x4.
// A is M x 512 row-major, B is 512 x 512 row-major, C is M x 512 row-major.

// ---------------------------------------------------------------------------
// ws layout (floats):
//   hmu : 384*512   @ 0        relu(x@w1mu + b1mu)
//   hlv : 384*512   @ 196608
//   gmu : 384*512   @ 393216   hmu@w2mu (no bias)
//   glv : 384*512   @ 589824   hlv@w2lv (no bias)
//   m1p : 6*512     @ 786432   y column-sum partials
//   m2p : 6*512     @ 789504   y column-sumsq partials
//   part: 96 dbl    @ 792576   (byte 3170304, 8B aligned)
// total ~3.17 MB
// ---------------------------------------------------------------------------

template<bool RELU>
__device__ __forceinline__ void gemm_tile(
    const float* __restrict__ A, const float* __restrict__ B,
    const float* __restrict__ bias, float* __restrict__ C,
    int m0, int n0,
    float (*As)[34], float (*Bs)[64])
{
    const int tid = threadIdx.x;
    const int tx = tid & 15;        // col group: n0 + tx*4
    const int ty = tid >> 4;        // rows: m0 + ty*2 + {0,1}

    // staging assignments
    const int r_a  = tid >> 3;      // 0..31  A-tile row
    const int kg_a = tid & 7;       // 0..7   A-tile k-group (4 floats)
    const int kr_b = tid >> 4;      // 0..15  B-tile row (and +16)
    const int cg_b = tid & 15;      // 0..15  B-tile col group

    float acc[2][4] = {};

    // preload iter 0
    float4 a_pf  = *(const float4*)&A[(size_t)(m0 + r_a) * 512 + kg_a * 4];
    float4 b_pf0 = *(const float4*)&B[(size_t)kr_b        * 512 + n0 + cg_b * 4];
    float4 b_pf1 = *(const float4*)&B[(size_t)(kr_b + 16) * 512 + n0 + cg_b * 4];

    for (int it = 0; it < 16; ++it) {
        __syncthreads();
        {   // store A transposed (k-major) + B natural
            float av[4];
            *(float4*)av = a_pf;
            #pragma unroll
            for (int j = 0; j < 4; ++j) As[kg_a * 4 + j][r_a] = av[j];
            *(float4*)&Bs[kr_b][cg_b * 4]      = b_pf0;
            *(float4*)&Bs[kr_b + 16][cg_b * 4] = b_pf1;
        }
        __syncthreads();

        if (it < 15) {  // issue next-iter loads; latency overlaps compute below
            const int k0n = (it + 1) * 32;
            a_pf  = *(const float4*)&A[(size_t)(m0 + r_a) * 512 + k0n + kg_a * 4];
            b_pf0 = *(const float4*)&B[(size_t)(k0n + kr_b)      * 512 + n0 + cg_b * 4];
            b_pf1 = *(const float4*)&B[(size_t)(k0n + kr_b + 16) * 512 + n0 + cg_b * 4];
        }

        #pragma unroll
        for (int kk = 0; kk < 32; ++kk) {
            const float a0 = As[kk][ty * 2 + 0];
            const float a1 = As[kk][ty * 2 + 1];
            const float4 bv = *(const float4*)&Bs[kk][tx * 4];
            acc[0][0] += a0 * bv.x; acc[0][1] += a0 * bv.y;
            acc[0][2] += a0 * bv.z; acc[0][3] += a0 * bv.w;
            acc[1][0] += a1 * bv.x; acc[1][1] += a1 * bv.y;
            acc[1][2] += a1 * bv.z; acc[1][3] += a1 * bv.w;
        }
    }

    float bb[4] = {0.f, 0.f, 0.f, 0.f};
    if (RELU) *(float4*)bb = *(const float4*)&bias[n0 + tx * 4];
    #pragma unroll
    for (int i = 0; i < 2; ++i) {
        float4 o;
        if (RELU) {
            o.x = fmaxf(acc[i][0] + bb[0], 0.f);
            o.y = fmaxf(acc[i][1] + bb[1], 0.f);
            o.z = fmaxf(acc[i][2] + bb[2], 0.f);
            o.w = fmaxf(acc[i][3] + bb[3], 0.f);
        } else {
            o.x = acc[i][0]; o.y = acc[i][1]; o.z = acc[i][2]; o.w = acc[i][3];
        }
        *(float4*)&C[(size_t)(m0 + ty * 2 + i) * 512 + n0 + tx * 4] = o;
    }
}

// Kernel 1: layer-1 GEMMs for both branches (blocks 0..191) + y column-moment
// partial blocks (192..197). 198 blocks x 256 threads.
__global__ __launch_bounds__(256) void k_layer1(
    const float* __restrict__ x,
    const float* __restrict__ w1mu, const float* __restrict__ b1mu,
    const float* __restrict__ w1lv, const float* __restrict__ b1lv,
    const float* __restrict__ y,
    float* __restrict__ hmu, float* __restrict__ hlv,
    float* __restrict__ m1p, float* __restrict__ m2p)
{
    __shared__ float As[32][34];
    __shared__ float Bs[32][64];

    const int b = blockIdx.x;
    const int tid = threadIdx.x;

    if (b >= 192) {
        // y column stats: block sb handles rows sb*64 .. sb*64+63, all 512 cols
        __shared__ float r1[2][512];
        __shared__ float r2[2][512];
        const int sb = b - 192;
        const int c4 = tid & 127;   // float4 col group (512 cols / 4)
        const int rh = tid >> 7;    // row half (0/1)
        const int r0 = sb * 64 + rh * 32;
        float s1[4] = {0.f, 0.f, 0.f, 0.f};
        float s2[4] = {0.f, 0.f, 0.f, 0.f};
        for (int r = 0; r < 32; ++r) {
            float v[4];
            *(float4*)v = *(const float4*)&y[(size_t)(r0 + r) * 512 + c4 * 4];
            #pragma unroll
            for (int j = 0; j < 4; ++j) { s1[j] += v[j]; s2[j] += v[j] * v[j]; }
        }
        #pragma unroll
        for (int j = 0; j < 4; ++j) { r1[rh][c4 * 4 + j] = s1[j]; r2[rh][c4 * 4 + j] = s2[j]; }
        __syncthreads();
        if (rh == 0) {
            float4 o1, o2;
            o1.x = s1[0] + r1[1][c4 * 4 + 0]; o1.y = s1[1] + r1[1][c4 * 4 + 1];
            o1.z = s1[2] + r1[1][c4 * 4 + 2]; o1.w = s1[3] + r1[1][c4 * 4 + 3];
            o2.x = s2[0] + r2[1][c4 * 4 + 0]; o2.y = s2[1] + r2[1][c4 * 4 + 1];
            o2.z = s2[2] + r2[1][c4 * 4 + 2]; o2.w = s2[3] + r2[1][c4 * 4 + 3];
            *(float4*)&m1p[sb * 512 + c4 * 4] = o1;
            *(float4*)&m2p[sb * 512 + c4 * 4] = o2;
        }
        return;
    }

    const int branch = b >> 7 >= 1 ? 1 : (b >= 96 ? 1 : 0); // b>=96 -> lv
    const int idx = branch ? b - 96 : b;
    const int m0 = (idx >> 3) * 32;   // 12 row tiles
    const int n0 = (idx & 7) * 64;    // 8 col tiles

    if (branch == 0)
        gemm_tile<true>(x, w1mu, b1mu, hmu, m0, n0, As, Bs);
    else
        gemm_tile<true>(x, w1lv, b1lv, hlv, m0, n0, As, Bs);
}

// Kernel 2: layer-2 GEMMs, raw (bias deferred to k3). 192 blocks.
__global__ __launch_bounds__(256) void k_layer2(
    const float* __restrict__ hmu, const float* __restrict__ hlv,
    const float* __restrict__ w2mu, const float* __restrict__ w2lv,
    float* __restrict__ gmu, float* __restrict__ glv)
{
    __shared__ float As[32][34];
    __shared__ float Bs[32][64];

    const int b = blockIdx.x;
    const int branch = b >= 96 ? 1 : 0;
    const int idx = branch ? b - 96 : b;
    const int m0 = (idx >> 3) * 32;
    const int n0 = (idx & 7) * 64;

    if (branch == 0)
        gemm_tile<false>(hmu, w2mu, nullptr, gmu, m0, n0, As, Bs);
    else
        gemm_tile<false>(hlv, w2lv, nullptr, glv, m0, n0, As, Bs);
}

// Kernel 3: elementwise epilogue + block reduction. 96 blocks x 256 threads,
// 2 float4 per thread (96*256*8 = 196608 elements).
__global__ __launch_bounds__(256) void k_epilogue(
    const float* __restrict__ gmu, const float* __restrict__ glv,
    const float* __restrict__ b2mu, const float* __restrict__ b2lv,
    const float* __restrict__ y,
    const float* __restrict__ m1p, const float* __restrict__ m2p,
    double* __restrict__ partials)
{
    __shared__ double wsum[4];
    const int tid = threadIdx.x;
    const float inv_b = 1.0f / (float)BSZ;

    float tsum = 0.f;
    #pragma unroll
    for (int jj = 0; jj < 2; ++jj) {
        const int e4 = blockIdx.x * 512 + tid * 2 + jj;   // float4 index
        const int col4 = e4 & 127;                        // f4 col group in row
        const size_t off = (size_t)e4 * 4;

        float gm[4], gl[4], yv[4], bm[4], bl[4], s1[4], s2[4];
        *(float4*)gm = *(const float4*)&gmu[off];
        *(float4*)gl = *(const float4*)&glv[off];
        *(float4*)yv = *(const float4*)&y[off];
        *(float4*)bm = *(const float4*)&b2mu[col4 * 4];
        *(float4*)bl = *(const float4*)&b2lv[col4 * 4];
        #pragma unroll
        for (int j = 0; j < 4; ++j) { s1[j] = 0.f; s2[j] = 0.f; }
        #pragma unroll
        for (int t = 0; t < 6; ++t) {
            float p1[4], p2[4];
            *(float4*)p1 = *(const float4*)&m1p[t * 512 + col4 * 4];
            *(float4*)p2 = *(const float4*)&m2p[t * 512 + col4 * 4];
            #pragma unroll
            for (int j = 0; j < 4; ++j) { s1[j] += p1[j]; s2[j] += p2[j]; }
        }
        #pragma unroll
        for (int j = 0; j < 4; ++j) {
            const float m1 = s1[j] * inv_b;
            const float m2 = s2[j] * inv_b;
            const float mu = gm[j] + bm[j];
            const float lv = tanhf(gl[j] + bl[j]);
            const float iv = expf(-lv);
            tsum += iv * ((yv[j] * yv[j] - m2) + 2.f * mu * (m1 - yv[j]));
        }
    }

    float s = tsum;
    #pragma unroll
    for (int off = 32; off > 0; off >>= 1) s += __shfl_down(s, off);
    if ((tid & 63) == 0) wsum[tid >> 6] = (double)s;
    __syncthreads();
    if (tid == 0)
        partials[blockIdx.x] = wsum[0] + wsum[1] + wsum[2] + wsum[3];
}

// Kernel 4: reduce 96 double partials -> scalar output.
__global__ void k_final(const double* __restrict__ partials, float* __restrict__ out)
{
    const int t = threadIdx.x;
    double v = partials[t] + (t < 32 ? partials[64 + t] : 0.0);
    #pragma unroll
    for (int off = 32; off > 0; off >>= 1) v += __shfl_down(v, off);
    if (t == 0) {
        // C0 = log1p(exp(-20)/383) — the broadcast-bug logsumexp constant
        const double C0 = 5.381602146862063e-12;
        out[0] = (float)(-0.5 * v / (double)BSZ - C0);
    }
}

extern "C" void kernel_launch(void* const* d_in, const int* in_sizes, int n_in,
                              void* d_out, int out_size, void* d_ws, size_t ws_size,
                              hipStream_t stream) {
    const float* x    = (const float*)d_in[0];
    const float* y    = (const float*)d_in[1];
    const float* w1mu = (const float*)d_in[2];
    const float* b1mu = (const float*)d_in[3];
    const float* w2mu = (const float*)d_in[4];
    const float* b2mu = (const float*)d_in[5];
    const float* w1lv = (const float*)d_in[6];
    const float* b1lv = (const float*)d_in[7];
    const float* w2lv = (const float*)d_in[8];
    const float* b2lv = (const float*)d_in[9];
    float* out = (float*)d_out;

    float* ws = (float*)d_ws;
    float* hmu = ws;
    float* hlv = ws + 196608;
    float* gmu = ws + 393216;
    float* glv = ws + 589824;
    float* m1p = ws + 786432;
    float* m2p = ws + 789504;
    double* partials = (double*)(ws + 792576);

    k_layer1<<<198, 256, 0, stream>>>(x, w1mu, b1mu, w1lv, b1lv, y,
                                      hmu, hlv, m1p, m2p);
    k_layer2<<<192, 256, 0, stream>>>(hmu, hlv, w2mu, w2lv, gmu, glv);
    k_epilogue<<<96, 256, 0, stream>>>(gmu, glv, b2mu, b2lv, y, m1p, m2p, partials);
    k_final<<<1, 64, 0, stream>>>(partials, out);
}